// Round 1
// baseline (77.828 us; speedup 1.0000x reference)
//
#include <hip/hip_runtime.h>

// IMPACT modality argmin:
//   per query b: u = users_emb[user_ids[b]]           (128 f32)
//                rows m in [1, nb_modalities[item]]:  item_emb[item*14+m] (128 f32)
//   p_m = ||u - v_m||^2 ; out = (argmin_m p_m - 1)/(nb-1) + 1
//
// 16 lanes per query; f64 accumulation of exact f32 diffs to sidestep
// f32 sum-order argmin flips vs the numpy reference.

#define M_TOT 14
#define CDIM 128

__global__ __launch_bounds__(256) void impact_argmin_kernel(
    const int* __restrict__ user_ids,
    const int* __restrict__ item_ids,
    const float* __restrict__ users_emb,   // [USER_N, 128]
    const float* __restrict__ item_emb,    // [ITEM_N*14, 128]
    const int* __restrict__ nb_mod,        // [ITEM_N]
    float* __restrict__ out,
    int B)
{
    int tid = blockIdx.x * blockDim.x + threadIdx.x;
    int q = tid >> 4;          // one query per 16-lane group
    int l = tid & 15;
    if (q >= B) return;

    int uid = user_ids[q];
    int iid = item_ids[q];
    int nb  = nb_mod[iid];     // in [2, 12]; valid modality cols are 1..nb

    // user row: 32 float4s, lanes 0..15 read two coalesced float4s each
    const float4* urow = (const float4*)(users_emb + (size_t)uid * CDIM);
    float4 u0 = urow[l];
    float4 u1 = urow[l + 16];

    double best = 1e300;
    int bidx = 1;

    const float4* ibase =
        (const float4*)(item_emb + ((size_t)iid * M_TOT + 1) * CDIM);

    for (int m = 1; m <= nb; ++m) {
        const float4* vrow = ibase + (size_t)(m - 1) * (CDIM / 4);
        float4 v0 = vrow[l];
        float4 v1 = vrow[l + 16];

        float d;
        double s = 0.0;
        d = u0.x - v0.x; s += (double)d * d;
        d = u0.y - v0.y; s += (double)d * d;
        d = u0.z - v0.z; s += (double)d * d;
        d = u0.w - v0.w; s += (double)d * d;
        d = u1.x - v1.x; s += (double)d * d;
        d = u1.y - v1.y; s += (double)d * d;
        d = u1.z - v1.z; s += (double)d * d;
        d = u1.w - v1.w; s += (double)d * d;

        // 16-lane butterfly reduce (xor masks < 16 stay within the group)
        s += __shfl_xor(s, 1);
        s += __shfl_xor(s, 2);
        s += __shfl_xor(s, 4);
        s += __shfl_xor(s, 8);

        // all 16 lanes hold the full sum; ascending m + strict '<'
        // == argmin first-occurrence semantics
        if (s < best) { best = s; bidx = m; }
    }

    if (l == 0)
        out[q] = (float)(bidx - 1) / (float)(nb - 1) + 1.0f;
}

extern "C" void kernel_launch(void* const* d_in, const int* in_sizes, int n_in,
                              void* d_out, int out_size, void* d_ws, size_t ws_size,
                              hipStream_t stream) {
    // inputs: 0 user_ids, 1 item_ids, 2 concept_ids (unused),
    //         3 users_emb_weight, 4 item_resp_emb_weight,
    //         5 mask (unused; equivalent to nb_modalities), 6 nb_modalities
    const int*   user_ids  = (const int*)d_in[0];
    const int*   item_ids  = (const int*)d_in[1];
    const float* users_emb = (const float*)d_in[3];
    const float* item_emb  = (const float*)d_in[4];
    const int*   nb_mod    = (const int*)d_in[6];
    float* out = (float*)d_out;

    int B = in_sizes[0];
    // 16 queries per 256-thread block
    int grid = (B + 15) / 16;
    impact_argmin_kernel<<<grid, 256, 0, stream>>>(
        user_ids, item_ids, users_emb, item_emb, nb_mod, out, B);
}